// Round 12
// baseline (200.716 us; speedup 1.0000x reference)
//
#include <hip/hip_runtime.h>
#include <hip/hip_bf16.h>
#include <stdint.h>

#define T_ 4
#define B_ 16
#define C_ 256
#define N_ 1024
#define HEADS_ 8
#define HD_ 32

typedef unsigned long long u64;
typedef unsigned char u8;

__device__ __forceinline__ u64 rf64(u64 v) {
  unsigned lo = __builtin_amdgcn_readfirstlane((unsigned)v);
  unsigned hi = __builtin_amdgcn_readfirstlane((unsigned)(v >> 32));
  return ((u64)hi << 32) | (u64)lo;
}

// ---------- prep: wqkv[256][768], wtp[c][256], BN tables (r11-verified) ------
__global__ __launch_bounds__(256) void prep_kernel(
    const float* __restrict__ qw, const float* __restrict__ kw,
    const float* __restrict__ vw, const float* __restrict__ pw,
    const float* __restrict__ qg, const float* __restrict__ qb2,
    const float* __restrict__ qmn, const float* __restrict__ qvr,
    const float* __restrict__ kg, const float* __restrict__ kb2,
    const float* __restrict__ kmn, const float* __restrict__ kvr,
    const float* __restrict__ vg, const float* __restrict__ vb2,
    const float* __restrict__ vmn, const float* __restrict__ vvr,
    const float* __restrict__ pg, const float* __restrict__ pb2,
    const float* __restrict__ pmn, const float* __restrict__ pvr,
    float* __restrict__ wqkv, float* __restrict__ wtp,
    float* __restrict__ bnt) {
  if (blockIdx.x < 256) {
    int c = blockIdx.x;
    int o = threadIdx.x;
    wqkv[c * 768 + o]       = qw[o * C_ + c];
    wqkv[c * 768 + 256 + o] = kw[o * C_ + c];
    wqkv[c * 768 + 512 + o] = vw[o * C_ + c];
    wtp[c * C_ + o]         = pw[o * C_ + c];
  } else {
    int c = threadIdx.x;
    float rs;
    rs = sqrtf(qvr[c] + 1e-5f);
    bnt[0 * C_ + c] = qg[c] / rs;
    bnt[1 * C_ + c] = qb2[c] - qmn[c] * qg[c] / rs;
    rs = sqrtf(kvr[c] + 1e-5f);
    bnt[2 * C_ + c] = kg[c] / rs;
    bnt[3 * C_ + c] = kb2[c] - kmn[c] * kg[c] / rs;
    rs = sqrtf(vvr[c] + 1e-5f);
    bnt[4 * C_ + c] = vg[c] / rs;
    bnt[5 * C_ + c] = vb2[c] - vmn[c] * vg[c] / rs;
    rs = sqrtf(pvr[c] + 1e-5f);
    bnt[6 * C_ + c] = pg[c] / rs;
    bnt[7 * C_ + c] = pb2[c] - pmn[c] * pg[c] / rs;
  }
}

// ---------- P0: shortcut LIF -> xs bitmasks [site][4 words], c = 64wd + bit --
__global__ __launch_bounds__(256) void lif_shortcut(const float* __restrict__ x,
                                                    u64* __restrict__ xsm) {
  int b = blockIdx.x >> 5;          // 32 n-tiles of 32
  int n0 = (blockIdx.x & 31) << 5;
  int tid = threadIdx.x;
  int l = tid & 63, w = tid >> 6;
  __shared__ float tile[C_ * 33];
  float v[32];
#pragma unroll
  for (int i = 0; i < 32; i++) v[i] = 0.f;
  int c = (w << 6) + l;             // this thread's channel
  for (int t = 0; t < T_; t++) {
    __syncthreads();
    const float* xp = x + (((size_t)t * B_ + b) * C_) * N_ + n0;
    for (int idx = tid; idx < C_ * 32; idx += 256) {
      int cc = idx >> 5, nn = idx & 31;
      tile[cc * 33 + nn] = xp[(size_t)cc * N_ + nn];
    }
    __syncthreads();
#pragma unroll
    for (int nn = 0; nn < 32; nn++) {
      float xv = tile[c * 33 + nn];
      float h = v[nn] + (xv - v[nn]) * 0.5f;   // tau=2 exact halving
      bool s = h >= 1.0f;
      v[nn] = s ? 0.f : h;                     // hard reset, detach
      u64 bal = __ballot(s);
      if (l == nn) xsm[(((size_t)t * B_ + b) * N_ + n0 + nn) * 4 + w] = bal;
    }
  }
}

// ---------- P1: 3-way-split sparse q/k/v conv + BN + LIF ----------
// 768 threads = 12 waves; waves [0..3]=q, [4..7]=k, [8..11]=v; wave-site ws=w&3
// owns sites nn = ws, ws+4. Each visit: ONE float4 load (matrix slice).
// lane l owns o = 4l+j; ballots word j, bit l <-> c = 4l+j (r11-verified).
__global__ __launch_bounds__(768) void qkv_split(
    const u64* __restrict__ xsm, const float* __restrict__ wqkv,
    const float* __restrict__ bnt, float* __restrict__ pkv,
    u64* __restrict__ qm_out, float* __restrict__ vout) {
  int b = blockIdx.x >> 7;
  int nt = blockIdx.x & 127;
  int n0 = nt << 3;
  int tid = threadIdx.x;
  int l = tid & 63;
  int w = tid >> 6;          // 0..11
  int m = w >> 2;            // 0=q, 1=k, 2=v
  int ws = w & 3;

  __shared__ u64 kball[8][4][4];   // [nn][t][j] k-spike ballots (1 KB)
  __shared__ int scnt[4][4][C_];   // v-wave cnt reduction (16 KB)

  float sc[4], sh[4];
#pragma unroll
  for (int j = 0; j < 4; j++) {
    int o = (l << 2) + j;
    sc[j] = bnt[(2 * m) * C_ + o];
    sh[j] = bnt[(2 * m + 1) * C_ + o];
  }

  unsigned spk[2] = {0u, 0u};      // v-waves: spike bits, bit = 4t+j per site

  for (int s = 0; s < 2; s++) {
    int nn = ws + (s << 2);        // 0..7
    int n = n0 + nn;
    float acc[4][4];               // [t][j]
#pragma unroll
    for (int t = 0; t < 4; t++)
#pragma unroll
      for (int j = 0; j < 4; j++) acc[t][j] = 0.f;
#pragma unroll
    for (int t = 0; t < 4; t++) {
      const u64* mp = xsm + ((((size_t)t * B_ + b) * N_ + n) << 2);
#pragma unroll
      for (int wd = 0; wd < 4; wd++) {
        u64 mm = rf64(mp[wd]);     // SGPR-resident walk (r7-verified)
        while (mm) {
          int c = (wd << 6) + __builtin_ctzll(mm);
          mm &= mm - 1;
          float4 r = *((const float4*)(wqkv + c * 768 + (m << 8)) + l);
          acc[t][0] += r.x; acc[t][1] += r.y;
          acc[t][2] += r.z; acc[t][3] += r.w;
        }
      }
    }
    // BN + LIF scan over t (r10-verified per-matrix structure)
    float vm[4] = {0.f, 0.f, 0.f, 0.f};
#pragma unroll
    for (int t = 0; t < 4; t++) {
      size_t site = ((size_t)t * B_ + b) * N_ + n;
      float vo[4];
#pragma unroll
      for (int j = 0; j < 4; j++) {
        float p = acc[t][j] * sc[j] + sh[j];
        float h = vm[j] + (p - vm[j]) * 0.5f;
        bool sp = h >= 1.0f;
        vm[j] = sp ? 0.f : h;
        vo[j] = sp ? 1.0f : 0.0f;
        u64 bal = __ballot(sp);
        if (m == 0) {
          if (l == (t << 2) + j) qm_out[(site << 2) + j] = bal;
        } else if (m == 1) {
          if (l == (t << 2) + j) kball[nn][t][j] = bal;
        } else {
          spk[s] |= (sp ? 1u : 0u) << ((t << 2) + j);
        }
      }
      if (m == 2) {
        // contiguous float4 vout store (r11-verified layout)
        float* vp = vout +
            ((((size_t)t * B_ + b) * HEADS_ + (l >> 3)) * (size_t)N_ + n) * HD_ +
            ((l & 7) << 2);
        float4 o4; o4.x = vo[0]; o4.y = vo[1]; o4.z = vo[2]; o4.w = vo[3];
        *(float4*)vp = o4;
      }
    }
  }
  __syncthreads();                 // kball complete

  // v-waves: kv counts over their 2 sites
  if (m == 2) {
    int cnt[4][4];
#pragma unroll
    for (int t = 0; t < 4; t++)
#pragma unroll
      for (int j = 0; j < 4; j++) cnt[t][j] = 0;
#pragma unroll
    for (int s = 0; s < 2; s++) {
      int nn = ws + (s << 2);
#pragma unroll
      for (int t = 0; t < 4; t++)
#pragma unroll
        for (int j = 0; j < 4; j++) {
          bool sv = (spk[s] >> ((t << 2) + j)) & 1u;
          bool sk = (kball[nn][t][j] >> l) & 1ull;
          cnt[t][j] += (sv && sk) ? 1 : 0;
        }
    }
#pragma unroll
    for (int t = 0; t < 4; t++)
#pragma unroll
      for (int j = 0; j < 4; j++) scnt[ws][t][(l << 2) + j] = cnt[t][j];
  }
  __syncthreads();
  // coalesced pkv write: [t][b][nt(128)][c] (r9-verified coalescing)
  for (int idx = tid; idx < 4 * C_; idx += 768) {
    int t = idx >> 8, c = idx & 255;
    int s = scnt[0][t][c] + scnt[1][t][c] + scnt[2][t][c] + scnt[3][t][c];
    pkv[(((size_t)t * B_ + b) * 128 + nt) * C_ + c] = (float)s;
  }
}

// ---------- P2: reduce kv partials + talking-heads LIF (r11-verified) --------
__global__ __launch_bounds__(256) void kv_lif_kernel(const float* __restrict__ pkv,
                                                     u64* __restrict__ kvsm) {
  int b = blockIdx.x;
  int tid = threadIdx.x;
  int l = tid & 63, j = tid >> 6;
  int c = (l << 2) + j;
  float v = 0.f;
  for (int t = 0; t < 4; t++) {
    const float* p = pkv + (((size_t)t * B_ + b) * 128) * C_ + c;
    float kv = 0.f;
#pragma unroll
    for (int i = 0; i < 128; i++) kv += p[(size_t)i * C_];  // exact ints
    float h = v + (kv - v) * 0.5f;
    bool s = h >= 0.5f;
    v = s ? 0.f : h;
    u64 bal = __ballot(s);
    if (l == t) kvsm[((size_t)t * B_ + b) * 4 + j] = bal;
  }
}

// ---------- P3: sparse proj + bias + BN + identity, with x prefetch ----------
// qm/kvs word j, bit li <-> c = 4li + j (r11-verified decode).
__global__ __launch_bounds__(256) void proj_sparse(
    const u64* __restrict__ qm, const u64* __restrict__ kvsm,
    const float* __restrict__ wtp, const float* __restrict__ bnt,
    const float* __restrict__ pbias, const float* __restrict__ x,
    float* __restrict__ out) {
  int tb = blockIdx.x >> 5;         // 64 (t,b) x 32 n-tiles of 32
  int n0 = (blockIdx.x & 31) << 5;
  int t = tb >> 4, b = tb & 15;
  int tid = threadIdx.x;
  int l = tid & 63, w = tid >> 6;
  __shared__ float tile[C_ * 33];
  u64 kvm[4];
#pragma unroll
  for (int j = 0; j < 4; j++) kvm[j] = kvsm[((size_t)t * B_ + b) * 4 + j];

  // prefetch epilogue x reads: overlaps HBM stream with the walk below
  int col = l & 31;
  int half = l >> 5;
  float xpre[32];
#pragma unroll
  for (int k = 0; k < 32; k++) {
    int r = (w << 1) + half + (k << 3);
    xpre[k] = x[(((size_t)t * B_ + b) * C_ + r) * N_ + n0 + col];
  }

  for (int nn = w; nn < 32; nn += 4) {
    int n = n0 + nn;
    float acc[4] = {0.f, 0.f, 0.f, 0.f};
    size_t site = ((size_t)t * B_ + b) * N_ + n;
    const u64* mp = qm + (site << 2);
#pragma unroll
    for (int j = 0; j < 4; j++) {
      u64 m = rf64(mp[j]) & kvm[j];
      while (m) {
        int li = __builtin_ctzll(m);
        m &= m - 1;
        int c = (li << 2) + j;      // c = 4*bit + j layout
        const float* rp = wtp + c * C_;
#pragma unroll
        for (int jj = 0; jj < 4; jj++) acc[jj] += rp[(jj << 6) + l];
      }
    }
#pragma unroll
    for (int jj = 0; jj < 4; jj++) tile[((jj << 6) + l) * 33 + nn] = acc[jj];
  }
  __syncthreads();
  // per-row epilogue, coalesced over n (verified math), x from prefetch regs
#pragma unroll
  for (int k = 0; k < 32; k++) {
    int r = (w << 1) + half + (k << 3);
    float val = tile[r * 33 + col];
    float z = (val + pbias[r]) * bnt[6 * C_ + r] + bnt[7 * C_ + r];
    size_t xi = (((size_t)t * B_ + b) * C_ + r) * N_ + n0 + col;
    out[xi] = z + xpre[k];
  }
}

// ---------- diagnostic: if ws too small, zero the output ----------
__global__ __launch_bounds__(256) void fill_zero_f32(float* p, size_t n) {
  size_t i = (size_t)blockIdx.x * 256 + threadIdx.x;
  if (i < n) p[i] = 0.0f;
}

extern "C" void kernel_launch(void* const* d_in, const int* in_sizes, int n_in,
                              void* d_out, int out_size, void* d_ws, size_t ws_size,
                              hipStream_t stream) {
  const float* x  = (const float*)d_in[0];
  const float* qw = (const float*)d_in[1];
  const float* qg = (const float*)d_in[2];
  const float* qb = (const float*)d_in[3];
  const float* qm = (const float*)d_in[4];
  const float* qv = (const float*)d_in[5];
  const float* kw = (const float*)d_in[6];
  const float* kg = (const float*)d_in[7];
  const float* kb = (const float*)d_in[8];
  const float* km = (const float*)d_in[9];
  const float* kv = (const float*)d_in[10];
  const float* vw = (const float*)d_in[11];
  const float* vg = (const float*)d_in[12];
  const float* vb2 = (const float*)d_in[13];
  const float* vm = (const float*)d_in[14];
  const float* vv = (const float*)d_in[15];
  const float* pw = (const float*)d_in[16];
  const float* pbias = (const float*)d_in[17];
  const float* pg = (const float*)d_in[18];
  const float* pb = (const float*)d_in[19];
  const float* pm = (const float*)d_in[20];
  const float* pv = (const float*)d_in[21];

  const size_t needed = 13644800ull;
  if (ws_size < needed) {
    size_t n = (size_t)out_size;
    fill_zero_f32<<<(unsigned)((n + 255) / 256), 256, 0, stream>>>(
        (float*)d_out, n);
    return;
  }

  char* ws = (char*)d_ws;
  float* wqkv = (float*)(ws + 0);         // 768 KB [256][768]
  float* wtp  = (float*)(ws + 789504);    // 256 KB [c][o]
  float* bnt  = (float*)(ws + 1051648);   // 8 KB
  u64*   xsm  = (u64*)  (ws + 1059840);   // 2 MB  [site][4 words], c = 64wd+bit
  u64*   qmm  = (u64*)  (ws + 3156992);   // 2 MB  [site][4 j-words], c = 4l+j
  float* pkv  = (float*)(ws + 5254144);   // 8 MB  [t][b][nt(128)][c]
  u64*   kvsm = (u64*)  (ws + 13642752);  // 2 KB  [t][b][4 j-words]

  float* out  = (float*)d_out;
  float* vout = out + (size_t)T_ * B_ * C_ * N_;

  prep_kernel<<<257, 256, 0, stream>>>(qw, kw, vw, pw,
                                       qg, qb, qm, qv, kg, kb, km, kv,
                                       vg, vb2, vm, vv, pg, pb, pm, pv,
                                       wqkv, wtp, bnt);
  lif_shortcut<<<512, 256, 0, stream>>>(x, xsm);
  qkv_split<<<2048, 768, 0, stream>>>(xsm, wqkv, bnt, pkv, qmm, vout);
  kv_lif_kernel<<<16, 256, 0, stream>>>(pkv, kvsm);
  proj_sparse<<<2048, 256, 0, stream>>>(qmm, kvsm, wtp, bnt, pbias, x, out);
}

// Round 13
// 160.481 us; speedup vs baseline: 1.2507x; 1.2507x over previous
//
#include <hip/hip_runtime.h>
#include <hip/hip_bf16.h>
#include <stdint.h>

#define T_ 4
#define B_ 16
#define C_ 256
#define N_ 1024
#define HEADS_ 8
#define HD_ 32
#define ZROW 256   // zero row index in wtq/wtk/wtv (257-row arrays)

typedef unsigned long long u64;
typedef unsigned char u8;

// ---------- prep: transpose weights to [c][o], rows 256 = zeros ----------
__global__ __launch_bounds__(256) void prep_transpose(
    const float* __restrict__ qw, const float* __restrict__ kw,
    const float* __restrict__ vw, const float* __restrict__ pw,
    float* __restrict__ wtq, float* __restrict__ wtk,
    float* __restrict__ wtv, float* __restrict__ wtp) {
  int c = blockIdx.x;
  int o = threadIdx.x;
  if (c < 256) {
    wtq[c * C_ + o] = qw[o * C_ + c];
    wtk[c * C_ + o] = kw[o * C_ + c];
    wtv[c * C_ + o] = vw[o * C_ + c];
    wtp[c * C_ + o] = pw[o * C_ + c];
  } else {
    wtq[ZROW * C_ + o] = 0.f;
    wtk[ZROW * C_ + o] = 0.f;
    wtv[ZROW * C_ + o] = 0.f;
  }
}

// ---------- prep: BN scale/shift tables (verified) ----------
__global__ __launch_bounds__(256) void prep_bn(
    const float* __restrict__ qg, const float* __restrict__ qb2,
    const float* __restrict__ qmn, const float* __restrict__ qvr,
    const float* __restrict__ kg, const float* __restrict__ kb2,
    const float* __restrict__ kmn, const float* __restrict__ kvr,
    const float* __restrict__ vg, const float* __restrict__ vb2,
    const float* __restrict__ vmn, const float* __restrict__ vvr,
    const float* __restrict__ pg, const float* __restrict__ pb2,
    const float* __restrict__ pmn, const float* __restrict__ pvr,
    float* __restrict__ bnt) {
  int c = threadIdx.x;
  float rs;
  rs = sqrtf(qvr[c] + 1e-5f);
  bnt[0 * C_ + c] = qg[c] / rs;
  bnt[1 * C_ + c] = qb2[c] - qmn[c] * qg[c] / rs;
  rs = sqrtf(kvr[c] + 1e-5f);
  bnt[2 * C_ + c] = kg[c] / rs;
  bnt[3 * C_ + c] = kb2[c] - kmn[c] * kg[c] / rs;
  rs = sqrtf(vvr[c] + 1e-5f);
  bnt[4 * C_ + c] = vg[c] / rs;
  bnt[5 * C_ + c] = vb2[c] - vmn[c] * vg[c] / rs;
  rs = sqrtf(pvr[c] + 1e-5f);
  bnt[6 * C_ + c] = pg[c] / rs;
  bnt[7 * C_ + c] = pb2[c] - pmn[c] * pg[c] / rs;
}

// ---------- P0: shortcut LIF -> xs bitmasks [site][4 words], c = 64w + l ----
__global__ __launch_bounds__(256) void lif_shortcut(const float* __restrict__ x,
                                                    u64* __restrict__ xsm) {
  int b = blockIdx.x >> 5;          // 32 n-tiles of 32
  int n0 = (blockIdx.x & 31) << 5;
  int tid = threadIdx.x;
  int l = tid & 63, w = tid >> 6;
  __shared__ float tile[C_ * 33];
  float v[32];
#pragma unroll
  for (int i = 0; i < 32; i++) v[i] = 0.f;
  int c = (w << 6) + l;             // this thread's channel
  for (int t = 0; t < T_; t++) {
    __syncthreads();
    const float* xp = x + (((size_t)t * B_ + b) * C_) * N_ + n0;
    for (int idx = tid; idx < C_ * 32; idx += 256) {
      int cc = idx >> 5, nn = idx & 31;
      tile[cc * 33 + nn] = xp[(size_t)cc * N_ + nn];
    }
    __syncthreads();
#pragma unroll
    for (int nn = 0; nn < 32; nn++) {
      float xv = tile[c * 33 + nn];
      float h = v[nn] + (xv - v[nn]) * 0.5f;   // tau=2 exact halving
      bool s = h >= 1.0f;
      v[nn] = s ? 0.f : h;                     // hard reset, detach
      u64 bal = __ballot(s);
      if (l == nn) xsm[(((size_t)t * B_ + b) * N_ + n0 + nn) * 4 + w] = bal;
    }
  }
}

// ---------- P1: sparse q/k/v conv + BN + LIF (r9 + 2-deep unrolled walk) ----
// grid = b(16) x nt(128 tiles of 8 n); wave wv owns sites nn = wv, wv+4.
// lane l owns out-channels o = 64j + l, j=0..3 (r9 convention).
__global__ __launch_bounds__(256) void qkv_sparse(
    const u64* __restrict__ xsm,
    const float* __restrict__ wtq, const float* __restrict__ wtk,
    const float* __restrict__ wtv, const float* __restrict__ bnt,
    float* __restrict__ pkv, u64* __restrict__ qm_out,
    float* __restrict__ vout) {
  int b = blockIdx.x >> 7;
  int nt = blockIdx.x & 127;
  int n0 = nt << 3;
  int tid = threadIdx.x;
  int l = tid & 63, wv = tid >> 6;
  float qs[4], qsh[4], ks[4], ksh[4], vsc[4], vsh[4];
#pragma unroll
  for (int j = 0; j < 4; j++) {
    int o = (j << 6) + l;
    qs[j]  = bnt[0 * C_ + o]; qsh[j] = bnt[1 * C_ + o];
    ks[j]  = bnt[2 * C_ + o]; ksh[j] = bnt[3 * C_ + o];
    vsc[j] = bnt[4 * C_ + o]; vsh[j] = bnt[5 * C_ + o];
  }
  int cnt[4][4];
#pragma unroll
  for (int t = 0; t < 4; t++)
#pragma unroll
    for (int j = 0; j < 4; j++) cnt[t][j] = 0;

  for (int nn = wv; nn < 8; nn += 4) {
    int n = n0 + nn;
    float aq[4][4], ak[4][4], av[4][4];   // [t][j]
#pragma unroll
    for (int t = 0; t < 4; t++)
#pragma unroll
      for (int j = 0; j < 4; j++) { aq[t][j] = 0.f; ak[t][j] = 0.f; av[t][j] = 0.f; }
#pragma unroll
    for (int t = 0; t < 4; t++) {
      const u64* mp = xsm + ((((size_t)t * B_ + b) * N_ + n) << 2);
#pragma unroll
      for (int wd = 0; wd < 4; wd++) {
        u64 m = mp[wd];                    // wave-uniform, register walk
        while (m) {
          // 2-deep unroll: c0 real, c1 real-or-zero-row (exact +0.0 pad)
          int c0 = (wd << 6) + __builtin_ctzll(m);
          m &= (m - 1);
          int c1 = ZROW;
          if (m) { c1 = (wd << 6) + __builtin_ctzll(m); m &= (m - 1); }
          const float* rq0 = wtq + c0 * C_;
          const float* rk0 = wtk + c0 * C_;
          const float* rv0 = wtv + c0 * C_;
          const float* rq1 = wtq + c1 * C_;
          const float* rk1 = wtk + c1 * C_;
          const float* rv1 = wtv + c1 * C_;
#pragma unroll
          for (int j = 0; j < 4; j++) {
            int o = (j << 6) + l;
            float q0 = rq0[o], k0 = rk0[o], v0 = rv0[o];
            float q1 = rq1[o], k1 = rk1[o], v1 = rv1[o];
            aq[t][j] += q0; ak[t][j] += k0; av[t][j] += v0;
            aq[t][j] += q1; ak[t][j] += k1; av[t][j] += v1;
          }
        }
      }
    }
    // BN + LIF scan over t (verified math)
#pragma unroll
    for (int j = 0; j < 4; j++) {
      int o = (j << 6) + l;
      float vq = 0.f, vk = 0.f, vv = 0.f;
#pragma unroll
      for (int t = 0; t < 4; t++) {
        float pq = aq[t][j] * qs[j] + qsh[j];
        float pk = ak[t][j] * ks[j] + ksh[j];
        float pv = av[t][j] * vsc[j] + vsh[j];
        float hq = vq + (pq - vq) * 0.5f;
        float hk = vk + (pk - vk) * 0.5f;
        float hv = vv + (pv - vv) * 0.5f;
        bool sq = hq >= 1.0f; vq = sq ? 0.f : hq;
        bool sk = hk >= 1.0f; vk = sk ? 0.f : hk;
        bool sv = hv >= 1.0f; vv = sv ? 0.f : hv;
        cnt[t][j] += (sk && sv) ? 1 : 0;
        vout[(((size_t)t * B_ + b) * HEADS_ + (o >> 5)) * ((size_t)N_ * HD_) +
             (size_t)n * HD_ + (o & 31)] = sv ? 1.0f : 0.0f;
        u64 bal = __ballot(sq);
        if (l == (t << 2) + j)
          qm_out[((((size_t)t * B_ + b) * N_ + n) << 2) + j] = bal;
      }
    }
  }
  // cross-wave reduction of kv partial counts (deterministic, no atomics)
  __shared__ int scnt[4][4][C_];
#pragma unroll
  for (int t = 0; t < 4; t++)
#pragma unroll
    for (int j = 0; j < 4; j++) scnt[wv][t][(j << 6) + l] = cnt[t][j];
  __syncthreads();
  // coalesced pkv write: layout [t][b][nt][c] -> 1 KB contiguous per t
  for (int idx = tid; idx < 4 * C_; idx += 256) {
    int t = idx >> 8, c = idx & 255;
    int s = scnt[0][t][c] + scnt[1][t][c] + scnt[2][t][c] + scnt[3][t][c];
    pkv[(((size_t)t * B_ + b) * 128 + nt) * C_ + c] = (float)s;
  }
}

// ---------- P2: reduce kv partials + talking-heads LIF (v_th=0.5) ----------
// thread c; wave j = c>>6, lane l = c&63; ballot word j, bit l <-> c = 64j+l.
__global__ __launch_bounds__(256) void kv_lif_kernel(const float* __restrict__ pkv,
                                                     u64* __restrict__ kvsm) {
  int b = blockIdx.x;
  int c = threadIdx.x;
  int l = c & 63, j = c >> 6;
  float v = 0.f;
  for (int t = 0; t < 4; t++) {
    const float* p = pkv + (((size_t)t * B_ + b) * 128) * C_ + c;
    float kv = 0.f;
#pragma unroll
    for (int i = 0; i < 128; i++) kv += p[(size_t)i * C_];  // exact ints
    float h = v + (kv - v) * 0.5f;
    bool s = h >= 0.5f;
    v = s ? 0.f : h;
    u64 bal = __ballot(s);
    if (l == t) kvsm[((size_t)t * B_ + b) * 4 + j] = bal;
  }
}

// ---------- P3: attn = q & kvs -> sparse proj + bias + BN + identity ----------
__global__ __launch_bounds__(256) void proj_sparse(
    const u64* __restrict__ qm, const u64* __restrict__ kvsm,
    const float* __restrict__ wtp, const float* __restrict__ bnt,
    const float* __restrict__ pbias, const float* __restrict__ x,
    float* __restrict__ out) {
  int tb = blockIdx.x >> 5;         // 64 (t,b) x 32 n-tiles of 32
  int n0 = (blockIdx.x & 31) << 5;
  int t = tb >> 4, b = tb & 15;
  int tid = threadIdx.x;
  int l = tid & 63, w = tid >> 6;
  __shared__ float tile[C_ * 33];
  u64 kvm[4];
#pragma unroll
  for (int wd = 0; wd < 4; wd++) kvm[wd] = kvsm[((size_t)t * B_ + b) * 4 + wd];
  for (int nn = w; nn < 32; nn += 4) {
    int n = n0 + nn;
    float acc[4] = {0.f, 0.f, 0.f, 0.f};
    const u64* mp = qm + ((((size_t)t * B_ + b) * N_ + n) << 2);
#pragma unroll
    for (int wd = 0; wd < 4; wd++) {
      u64 m = mp[wd] & kvm[wd];
      while (m) {
        int c = (wd << 6) + __builtin_ctzll(m);
        m &= (m - 1);
        const float* rp = wtp + c * C_;
#pragma unroll
        for (int j = 0; j < 4; j++) acc[j] += rp[(j << 6) + l];
      }
    }
#pragma unroll
    for (int j = 0; j < 4; j++) tile[((j << 6) + l) * 33 + nn] = acc[j];
  }
  __syncthreads();
  // per-row epilogue, coalesced over n (verified math)
  int col = l & 31;
  int half = l >> 5;
  for (int r = (w << 1) + half; r < C_; r += 8) {
    float val = tile[r * 33 + col];
    float z = (val + pbias[r]) * bnt[6 * C_ + r] + bnt[7 * C_ + r];
    size_t xi = (((size_t)t * B_ + b) * C_ + r) * N_ + n0 + col;
    out[xi] = z + x[xi];
  }
}

// ---------- diagnostic: if ws too small, zero the output ----------
__global__ __launch_bounds__(256) void fill_zero_f32(float* p, size_t n) {
  size_t i = (size_t)blockIdx.x * 256 + threadIdx.x;
  if (i < n) p[i] = 0.0f;
}

extern "C" void kernel_launch(void* const* d_in, const int* in_sizes, int n_in,
                              void* d_out, int out_size, void* d_ws, size_t ws_size,
                              hipStream_t stream) {
  const float* x  = (const float*)d_in[0];
  const float* qw = (const float*)d_in[1];
  const float* qg = (const float*)d_in[2];
  const float* qb = (const float*)d_in[3];
  const float* qm = (const float*)d_in[4];
  const float* qv = (const float*)d_in[5];
  const float* kw = (const float*)d_in[6];
  const float* kg = (const float*)d_in[7];
  const float* kb = (const float*)d_in[8];
  const float* km = (const float*)d_in[9];
  const float* kv = (const float*)d_in[10];
  const float* vw = (const float*)d_in[11];
  const float* vg = (const float*)d_in[12];
  const float* vb2 = (const float*)d_in[13];
  const float* vm = (const float*)d_in[14];
  const float* vv = (const float*)d_in[15];
  const float* pw = (const float*)d_in[16];
  const float* pbias = (const float*)d_in[17];
  const float* pg = (const float*)d_in[18];
  const float* pb = (const float*)d_in[19];
  const float* pm = (const float*)d_in[20];
  const float* pv = (const float*)d_in[21];

  const size_t needed = 13647872ull;
  if (ws_size < needed) {
    size_t n = (size_t)out_size;
    fill_zero_f32<<<(unsigned)((n + 255) / 256), 256, 0, stream>>>(
        (float*)d_out, n);
    return;
  }

  char* ws = (char*)d_ws;
  float* wtq = (float*)(ws + 0);         // 257x256 floats (row 256 = 0)
  float* wtk = (float*)(ws + 263168);    // 257x256
  float* wtv = (float*)(ws + 526336);    // 257x256
  float* wtp = (float*)(ws + 789504);    // 256 KB [c][o]
  float* bnt = (float*)(ws + 1051648);   // 8 KB
  u64*   xsm = (u64*)  (ws + 1059840);   // 2 MB  [site][4 words], c = 64w+l
  u64*   qmm = (u64*)  (ws + 3156992);   // 2 MB  [site][4 words], c = 64j+l
  float* pkv = (float*)(ws + 5254144);   // 8 MB  [t][b][nt(128)][c]
  u64*   kvsm = (u64*) (ws + 13642752);  // 2 KB  [t][b][4 words]

  float* out  = (float*)d_out;
  float* vout = out + (size_t)T_ * B_ * C_ * N_;

  prep_transpose<<<257, 256, 0, stream>>>(qw, kw, vw, pw, wtq, wtk, wtv, wtp);
  prep_bn<<<1, 256, 0, stream>>>(qg, qb, qm, qv, kg, kb, km, kv,
                                 vg, vb2, vm, vv, pg, pb, pm, pv, bnt);
  lif_shortcut<<<512, 256, 0, stream>>>(x, xsm);
  qkv_sparse<<<2048, 256, 0, stream>>>(xsm, wtq, wtk, wtv, bnt, pkv, qmm, vout);
  kv_lif_kernel<<<16, 256, 0, stream>>>(pkv, kvsm);
  proj_sparse<<<2048, 256, 0, stream>>>(qmm, kvsm, wtp, bnt, pbias, x, out);
}

// Round 14
// 142.214 us; speedup vs baseline: 1.4114x; 1.1284x over previous
//
#include <hip/hip_runtime.h>
#include <hip/hip_bf16.h>
#include <stdint.h>

#define T_ 4
#define B_ 16
#define C_ 256
#define N_ 1024
#define HEADS_ 8
#define HD_ 32

typedef unsigned long long u64;
typedef unsigned char u8;

// ---------- prep: fused weight transpose [c][o] + BN tables ----------
__global__ __launch_bounds__(256) void prep_kernel(
    const float* __restrict__ qw, const float* __restrict__ kw,
    const float* __restrict__ vw, const float* __restrict__ pw,
    const float* __restrict__ qg, const float* __restrict__ qb2,
    const float* __restrict__ qmn, const float* __restrict__ qvr,
    const float* __restrict__ kg, const float* __restrict__ kb2,
    const float* __restrict__ kmn, const float* __restrict__ kvr,
    const float* __restrict__ vg, const float* __restrict__ vb2,
    const float* __restrict__ vmn, const float* __restrict__ vvr,
    const float* __restrict__ pg, const float* __restrict__ pb2,
    const float* __restrict__ pmn, const float* __restrict__ pvr,
    float* __restrict__ wtq, float* __restrict__ wtk,
    float* __restrict__ wtv, float* __restrict__ wtp,
    float* __restrict__ bnt) {
  if (blockIdx.x < 256) {
    int c = blockIdx.x;
    int o = threadIdx.x;
    wtq[c * C_ + o] = qw[o * C_ + c];
    wtk[c * C_ + o] = kw[o * C_ + c];
    wtv[c * C_ + o] = vw[o * C_ + c];
    wtp[c * C_ + o] = pw[o * C_ + c];
  } else {
    int c = threadIdx.x;
    float rs;
    rs = sqrtf(qvr[c] + 1e-5f);
    bnt[0 * C_ + c] = qg[c] / rs;
    bnt[1 * C_ + c] = qb2[c] - qmn[c] * qg[c] / rs;
    rs = sqrtf(kvr[c] + 1e-5f);
    bnt[2 * C_ + c] = kg[c] / rs;
    bnt[3 * C_ + c] = kb2[c] - kmn[c] * kg[c] / rs;
    rs = sqrtf(vvr[c] + 1e-5f);
    bnt[4 * C_ + c] = vg[c] / rs;
    bnt[5 * C_ + c] = vb2[c] - vmn[c] * vg[c] / rs;
    rs = sqrtf(pvr[c] + 1e-5f);
    bnt[6 * C_ + c] = pg[c] / rs;
    bnt[7 * C_ + c] = pb2[c] - pmn[c] * pg[c] / rs;
  }
}

// ---------- P0: shortcut LIF -> xs bitmasks [site][4 words], c = 64w + l ----
__global__ __launch_bounds__(256) void lif_shortcut(const float* __restrict__ x,
                                                    u64* __restrict__ xsm) {
  int b = blockIdx.x >> 5;          // 32 n-tiles of 32
  int n0 = (blockIdx.x & 31) << 5;
  int tid = threadIdx.x;
  int l = tid & 63, w = tid >> 6;
  __shared__ float tile[C_ * 33];
  float v[32];
#pragma unroll
  for (int i = 0; i < 32; i++) v[i] = 0.f;
  int c = (w << 6) + l;             // this thread's channel
  for (int t = 0; t < T_; t++) {
    __syncthreads();
    const float* xp = x + (((size_t)t * B_ + b) * C_) * N_ + n0;
    for (int idx = tid; idx < C_ * 32; idx += 256) {
      int cc = idx >> 5, nn = idx & 31;
      tile[cc * 33 + nn] = xp[(size_t)cc * N_ + nn];
    }
    __syncthreads();
#pragma unroll
    for (int nn = 0; nn < 32; nn++) {
      float xv = tile[c * 33 + nn];
      float h = v[nn] + (xv - v[nn]) * 0.5f;   // tau=2 exact halving
      bool s = h >= 1.0f;
      v[nn] = s ? 0.f : h;                     // hard reset, detach
      u64 bal = __ballot(s);
      if (l == nn) xsm[(((size_t)t * B_ + b) * N_ + n0 + nn) * 4 + w] = bal;
    }
  }
}

// ---------- P1: sparse q/k/v conv + BN + LIF (r9-verbatim best) ----------
// grid = b(16) x nt(128 tiles of 8 n); wave wv owns sites nn = wv, wv+4.
// lane l owns out-channels o = 64j + l, j=0..3.
__global__ __launch_bounds__(256) void qkv_sparse(
    const u64* __restrict__ xsm,
    const float* __restrict__ wtq, const float* __restrict__ wtk,
    const float* __restrict__ wtv, const float* __restrict__ bnt,
    float* __restrict__ pkv, u64* __restrict__ qm_out,
    float* __restrict__ vout) {
  int b = blockIdx.x >> 7;
  int nt = blockIdx.x & 127;
  int n0 = nt << 3;
  int tid = threadIdx.x;
  int l = tid & 63, wv = tid >> 6;
  float qs[4], qsh[4], ks[4], ksh[4], vsc[4], vsh[4];
#pragma unroll
  for (int j = 0; j < 4; j++) {
    int o = (j << 6) + l;
    qs[j]  = bnt[0 * C_ + o]; qsh[j] = bnt[1 * C_ + o];
    ks[j]  = bnt[2 * C_ + o]; ksh[j] = bnt[3 * C_ + o];
    vsc[j] = bnt[4 * C_ + o]; vsh[j] = bnt[5 * C_ + o];
  }
  int cnt[4][4];
#pragma unroll
  for (int t = 0; t < 4; t++)
#pragma unroll
    for (int j = 0; j < 4; j++) cnt[t][j] = 0;

  for (int nn = wv; nn < 8; nn += 4) {
    int n = n0 + nn;
    float aq[4][4], ak[4][4], av[4][4];   // [t][j]
#pragma unroll
    for (int t = 0; t < 4; t++)
#pragma unroll
      for (int j = 0; j < 4; j++) { aq[t][j] = 0.f; ak[t][j] = 0.f; av[t][j] = 0.f; }
#pragma unroll
    for (int t = 0; t < 4; t++) {
      const u64* mp = xsm + ((((size_t)t * B_ + b) * N_ + n) << 2);
#pragma unroll
      for (int wd = 0; wd < 4; wd++) {
        u64 m = mp[wd];                    // wave-uniform, register walk
        while (m) {
          int c = (wd << 6) + __builtin_ctzll(m);
          m &= (m - 1);
          const float* rq = wtq + c * C_;
          const float* rk = wtk + c * C_;
          const float* rv = wtv + c * C_;
#pragma unroll
          for (int j = 0; j < 4; j++) {
            int o = (j << 6) + l;
            aq[t][j] += rq[o];
            ak[t][j] += rk[o];
            av[t][j] += rv[o];
          }
        }
      }
    }
    // BN + LIF scan over t (verified math)
#pragma unroll
    for (int j = 0; j < 4; j++) {
      int o = (j << 6) + l;
      float vq = 0.f, vk = 0.f, vv = 0.f;
#pragma unroll
      for (int t = 0; t < 4; t++) {
        float pq = aq[t][j] * qs[j] + qsh[j];
        float pk = ak[t][j] * ks[j] + ksh[j];
        float pv = av[t][j] * vsc[j] + vsh[j];
        float hq = vq + (pq - vq) * 0.5f;
        float hk = vk + (pk - vk) * 0.5f;
        float hv = vv + (pv - vv) * 0.5f;
        bool sq = hq >= 1.0f; vq = sq ? 0.f : hq;
        bool sk = hk >= 1.0f; vk = sk ? 0.f : hk;
        bool sv = hv >= 1.0f; vv = sv ? 0.f : hv;
        cnt[t][j] += (sk && sv) ? 1 : 0;
        vout[(((size_t)t * B_ + b) * HEADS_ + (o >> 5)) * ((size_t)N_ * HD_) +
             (size_t)n * HD_ + (o & 31)] = sv ? 1.0f : 0.0f;
        u64 bal = __ballot(sq);
        if (l == (t << 2) + j)
          qm_out[((((size_t)t * B_ + b) * N_ + n) << 2) + j] = bal;
      }
    }
  }
  // cross-wave reduction of kv partial counts (deterministic, no atomics)
  __shared__ int scnt[4][4][C_];
#pragma unroll
  for (int t = 0; t < 4; t++)
#pragma unroll
    for (int j = 0; j < 4; j++) scnt[wv][t][(j << 6) + l] = cnt[t][j];
  __syncthreads();
  // coalesced pkv write: layout [t][b][nt][c] -> 1 KB contiguous per t
  for (int idx = tid; idx < 4 * C_; idx += 256) {
    int t = idx >> 8, c = idx & 255;
    int s = scnt[0][t][c] + scnt[1][t][c] + scnt[2][t][c] + scnt[3][t][c];
    pkv[(((size_t)t * B_ + b) * 128 + nt) * C_ + c] = (float)s;
  }
}

// ---------- P2: reduce kv partials + talking-heads LIF (wide, 1024 thr) -----
// block b; thread = (qtr, c); quarter-sums in LDS (exact ints, order-free),
// then waves 0-3 (c = 64j + l) do the LIF scan + ballots (r9 kvsm layout).
__global__ __launch_bounds__(1024) void kv_lif_kernel(const float* __restrict__ pkv,
                                                      u64* __restrict__ kvsm) {
  int b = blockIdx.x;
  int tid = threadIdx.x;
  int c = tid & 255, qtr = tid >> 8;
  __shared__ float part[4][4][C_];   // [qtr][t][c]
#pragma unroll
  for (int t = 0; t < 4; t++) {
    const float* p = pkv + ((((size_t)t * B_ + b) * 128) + (qtr << 5)) * C_ + c;
    float s = 0.f;
#pragma unroll
    for (int i = 0; i < 32; i++) s += p[(size_t)i * C_];   // exact ints
    part[qtr][t][c] = s;
  }
  __syncthreads();
  if (tid < 256) {
    int l = c & 63, j = c >> 6;
    float v = 0.f;
#pragma unroll
    for (int t = 0; t < 4; t++) {
      float kv = part[0][t][c] + part[1][t][c] + part[2][t][c] + part[3][t][c];
      float h = v + (kv - v) * 0.5f;
      bool s = h >= 0.5f;
      v = s ? 0.f : h;
      u64 bal = __ballot(s);
      if (l == t) kvsm[((size_t)t * B_ + b) * 4 + j] = bal;
    }
  }
}

// ---------- P3: attn = q & kvs -> sparse proj + bias + BN + identity ----------
__global__ __launch_bounds__(256) void proj_sparse(
    const u64* __restrict__ qm, const u64* __restrict__ kvsm,
    const float* __restrict__ wtp, const float* __restrict__ bnt,
    const float* __restrict__ pbias, const float* __restrict__ x,
    float* __restrict__ out) {
  int tb = blockIdx.x >> 5;         // 64 (t,b) x 32 n-tiles of 32
  int n0 = (blockIdx.x & 31) << 5;
  int t = tb >> 4, b = tb & 15;
  int tid = threadIdx.x;
  int l = tid & 63, w = tid >> 6;
  __shared__ float tile[C_ * 33];
  u64 kvm[4];
#pragma unroll
  for (int wd = 0; wd < 4; wd++) kvm[wd] = kvsm[((size_t)t * B_ + b) * 4 + wd];
  for (int nn = w; nn < 32; nn += 4) {
    int n = n0 + nn;
    float acc[4] = {0.f, 0.f, 0.f, 0.f};
    const u64* mp = qm + ((((size_t)t * B_ + b) * N_ + n) << 2);
#pragma unroll
    for (int wd = 0; wd < 4; wd++) {
      u64 m = mp[wd] & kvm[wd];
      while (m) {
        int c = (wd << 6) + __builtin_ctzll(m);
        m &= (m - 1);
        const float* rp = wtp + c * C_;
#pragma unroll
        for (int j = 0; j < 4; j++) acc[j] += rp[(j << 6) + l];
      }
    }
#pragma unroll
    for (int j = 0; j < 4; j++) tile[((j << 6) + l) * 33 + nn] = acc[j];
  }
  __syncthreads();
  // per-row epilogue, coalesced over n (verified math)
  int col = l & 31;
  int half = l >> 5;
  for (int r = (w << 1) + half; r < C_; r += 8) {
    float val = tile[r * 33 + col];
    float z = (val + pbias[r]) * bnt[6 * C_ + r] + bnt[7 * C_ + r];
    size_t xi = (((size_t)t * B_ + b) * C_ + r) * N_ + n0 + col;
    out[xi] = z + x[xi];
  }
}

// ---------- diagnostic: if ws too small, zero the output ----------
__global__ __launch_bounds__(256) void fill_zero_f32(float* p, size_t n) {
  size_t i = (size_t)blockIdx.x * 256 + threadIdx.x;
  if (i < n) p[i] = 0.0f;
}

extern "C" void kernel_launch(void* const* d_in, const int* in_sizes, int n_in,
                              void* d_out, int out_size, void* d_ws, size_t ws_size,
                              hipStream_t stream) {
  const float* x  = (const float*)d_in[0];
  const float* qw = (const float*)d_in[1];
  const float* qg = (const float*)d_in[2];
  const float* qb = (const float*)d_in[3];
  const float* qm = (const float*)d_in[4];
  const float* qv = (const float*)d_in[5];
  const float* kw = (const float*)d_in[6];
  const float* kg = (const float*)d_in[7];
  const float* kb = (const float*)d_in[8];
  const float* km = (const float*)d_in[9];
  const float* kv = (const float*)d_in[10];
  const float* vw = (const float*)d_in[11];
  const float* vg = (const float*)d_in[12];
  const float* vb2 = (const float*)d_in[13];
  const float* vm = (const float*)d_in[14];
  const float* vv = (const float*)d_in[15];
  const float* pw = (const float*)d_in[16];
  const float* pbias = (const float*)d_in[17];
  const float* pg = (const float*)d_in[18];
  const float* pb = (const float*)d_in[19];
  const float* pm = (const float*)d_in[20];
  const float* pv = (const float*)d_in[21];

  const size_t needed = 13641728ull;
  if (ws_size < needed) {
    size_t n = (size_t)out_size;
    fill_zero_f32<<<(unsigned)((n + 255) / 256), 256, 0, stream>>>(
        (float*)d_out, n);
    return;
  }

  char* ws = (char*)d_ws;
  float* wtq = (float*)(ws + 0);         // 256 KB [c][o]
  float* wtk = (float*)(ws + 262144);    // 256 KB
  float* wtv = (float*)(ws + 524288);    // 256 KB
  float* wtp = (float*)(ws + 786432);    // 256 KB
  float* bnt = (float*)(ws + 1048576);   // 8 KB
  u64*   xsm = (u64*)  (ws + 1056768);   // 2 MB  [site][4 words], c = 64w+l
  u64*   qmm = (u64*)  (ws + 3153920);   // 2 MB  [site][4 words], c = 64j+l
  float* pkv = (float*)(ws + 5251072);   // 8 MB  [t][b][nt(128)][c]
  u64*   kvsm = (u64*) (ws + 13639680);  // 2 KB  [t][b][4 words]

  float* out  = (float*)d_out;
  float* vout = out + (size_t)T_ * B_ * C_ * N_;

  prep_kernel<<<257, 256, 0, stream>>>(qw, kw, vw, pw,
                                       qg, qb, qm, qv, kg, kb, km, kv,
                                       vg, vb2, vm, vv, pg, pb, pm, pv,
                                       wtq, wtk, wtv, wtp, bnt);
  lif_shortcut<<<512, 256, 0, stream>>>(x, xsm);
  qkv_sparse<<<2048, 256, 0, stream>>>(xsm, wtq, wtk, wtv, bnt, pkv, qmm, vout);
  kv_lif_kernel<<<16, 1024, 0, stream>>>(pkv, kvsm);
  proj_sparse<<<2048, 256, 0, stream>>>(qmm, kvsm, wtp, bnt, pbias, x, out);
}